// Round 1
// baseline (30.081 us; speedup 1.0000x reference)
//
#include <hip/hip_runtime.h>
#include <math.h>

#define PATCH 512
#define SLACK 64
#define STEP  (PATCH - SLACK)   /* 448 */
#define HS    (SLACK / 2)       /* 32  */

// ---------------------------------------------------------------------------
// Kernel 1: out = (i > 0) ? y : 0     (full plane, float4-vectorized)
// ---------------------------------------------------------------------------
__global__ void copy_base_kernel(const float* __restrict__ y,
                                 float* __restrict__ out,
                                 const int* __restrict__ ip,
                                 int n4) {
    int idx = blockIdx.x * blockDim.x + threadIdx.x;
    if (idx >= n4) return;
    const int i = *ip;  // scalar, L1/L2-broadcast
    const float4* __restrict__ y4 = (const float4*)y;
    float4* __restrict__ o4 = (float4*)out;
    if (i > 0) {
        o4[idx] = y4[idx];
    } else {
        o4[idx] = make_float4(0.f, 0.f, 0.f, 0.f);
    }
}

// ---------------------------------------------------------------------------
// Kernel 2: conv3x3(+bias, sigmoid) over the paste rectangle, written in place
// into out. All make_grid / paste_coords geometry recomputed from device i.
// x is NHWC int32 (0..255), value = x/255. W is OIHW (1,3,3,3).
// ---------------------------------------------------------------------------
__global__ void patch_conv_kernel(const int* __restrict__ x,
                                  const float* __restrict__ Wt,
                                  const float* __restrict__ bp,
                                  const int* __restrict__ ip,
                                  float* __restrict__ out,
                                  int H, int W) {
    const int i = *ip;

    // --- make_grid geometry ---
    const int gh = (H - PATCH + STEP - 1) / STEP + 1;
    const int gw = (W - PATCH + STEP - 1) / STEP + 1;
    const int r = i / gw;
    const int c = i % gw;
    const int gyr = min(PATCH + r * STEP, H);
    const int gxc = min(PATCH + c * STEP, W);
    const int p0 = max(gyr - PATCH, 0);   // patch top in image
    const int p1 = max(gxc - PATCH, 0);   // patch left in image

    // --- paste_coords ---
    const int gy_m2 = min(PATCH + (gh - 2) * STEP, H);
    const int gx_m2 = min(PATCH + (gw - 2) * STEP, W);
    const int gy_m1 = min(PATCH + (gh - 1) * STEP, H);
    const int gx_m1 = min(PATCH + (gw - 1) * STEP, W);
    const int lh0 = (gy_m2 - (gy_m1 - PATCH)) / 2;
    const int lh1 = (gx_m2 - (gx_m1 - PATCH)) / 2;

    const int di0 = (r == 0) ? 0 : ((r == gh - 1) ? lh0 : HS);
    const int di1 = (c == 0) ? 0 : ((c == gw - 1) ? lh1 : HS);
    const int di2 = (r < gh - 1) ? (PATCH - HS) : PATCH;  // slice end clamped
    const int di3 = (c < gw - 1) ? (PATCH - HS) : PATCH;

    const int gi0 = p0 + di0;   // paste dest top in image
    const int gi1 = p1 + di1;   // paste dest left in image
    const int ph = di2 - di0;   // paste height
    const int pw = di3 - di1;   // paste width

    const int tx = blockIdx.x * blockDim.x + threadIdx.x;
    const int ty = blockIdx.y * blockDim.y + threadIdx.y;
    if (ty >= ph || tx >= pw) return;

    const int py = di0 + ty;    // patch-coords of this output pixel
    const int px = di1 + tx;

    const float bias = *bp;
    const float inv255 = 1.0f / 255.0f;

    float acc = bias;
#pragma unroll
    for (int ky = 0; ky < 3; ++ky) {
        const int ppy = py + ky - 1;
        if (ppy < 0 || ppy >= PATCH) continue;   // zero-pad at patch border
        const int ih = p0 + ppy;
#pragma unroll
        for (int kx = 0; kx < 3; ++kx) {
            const int ppx = px + kx - 1;
            if (ppx < 0 || ppx >= PATCH) continue;
            const int iw = p1 + ppx;
            const int* __restrict__ xp = x + ((size_t)ih * W + iw) * 3;
            const float w0 = Wt[0 * 9 + ky * 3 + kx];
            const float w1 = Wt[1 * 9 + ky * 3 + kx];
            const float w2 = Wt[2 * 9 + ky * 3 + kx];
            acc += w0 * ((float)xp[0] * inv255)
                 + w1 * ((float)xp[1] * inv255)
                 + w2 * ((float)xp[2] * inv255);
        }
    }

    const float v = 1.0f / (1.0f + expf(-acc));
    out[(size_t)(gi0 + ty) * W + (gi1 + tx)] = v;
}

// ---------------------------------------------------------------------------
extern "C" void kernel_launch(void* const* d_in, const int* in_sizes, int n_in,
                              void* d_out, int out_size, void* d_ws, size_t ws_size,
                              hipStream_t stream) {
    const int*   x  = (const int*)d_in[0];    // (1,H,W,3) int32
    const float* y  = (const float*)d_in[1];  // (1,1,H,W) f32
    const float* Wt = (const float*)d_in[2];  // (1,3,3,3) f32
    const float* b  = (const float*)d_in[3];  // (1,) f32
    const int*   ip = (const int*)d_in[4];    // scalar i
    float* out = (float*)d_out;

    // H = W (square plane); out_size = H*W
    int H = 1;
    while ((long long)(H + 1) * (H + 1) <= (long long)out_size) ++H;
    const int Wd = H;

    // Kernel 1: full-plane base copy (float4)
    const int n4 = (H * Wd) / 4;
    const int threads = 256;
    const int blocks = (n4 + threads - 1) / threads;
    copy_base_kernel<<<blocks, threads, 0, stream>>>(y, out, ip, n4);

    // Kernel 2: paste rectangle is at most PATCH x PATCH
    dim3 blk(32, 8);
    dim3 grd((PATCH + blk.x - 1) / blk.x, (PATCH + blk.y - 1) / blk.y);
    patch_conv_kernel<<<grd, blk, 0, stream>>>(x, Wt, b, ip, out, H, Wd);
}